// Round 1
// baseline (390.969 us; speedup 1.0000x reference)
//
#include <hip/hip_runtime.h>
#include <hip/hip_bf16.h>
#include <stdint.h>

#define M_TOK 8192
#define N_OUT 4096
#define K_IN  4096

#define BM 128
#define BN 128
#define BK 32
#define NT (K_IN / BK)   // 128 K-steps

typedef __attribute__((ext_vector_type(8))) __bf16 bf16x8;
typedef __attribute__((ext_vector_type(4))) float  f32x4;

#define AS1 __attribute__((address_space(1)))
#define AS3 __attribute__((address_space(3)))
// global -> LDS async DMA, 16B per lane. LDS dest is wave-uniform base + lane*16.
#define GLOAD_LDS16(g, l) \
  __builtin_amdgcn_global_load_lds((AS1 void*)(g), (AS3 void*)(l), 16, 0, 0)

// ---------------- prep: x fp32 -> bf16 (RNE via fptrunc) ----------------
__global__ __launch_bounds__(256) void cvt_x_bf16(const float4* __restrict__ x,
                                                  ushort4* __restrict__ o, int n4) {
  int i = blockIdx.x * blockDim.x + threadIdx.x;
  int stride = gridDim.x * blockDim.x;
  for (; i < n4; i += stride) {
    float4 v = x[i];
    ushort4 r;
    r.x = __builtin_bit_cast(unsigned short, (__bf16)v.x);
    r.y = __builtin_bit_cast(unsigned short, (__bf16)v.y);
    r.z = __builtin_bit_cast(unsigned short, (__bf16)v.z);
    r.w = __builtin_bit_cast(unsigned short, (__bf16)v.w);
    o[i] = r;
  }
}

// ---------------- prep: W fp32 -> sign in bf16 {0xBF80,-1 | 0 | 0x3F80,+1} ----
__global__ __launch_bounds__(256) void sgn_w_bf16(const float4* __restrict__ w,
                                                  ushort4* __restrict__ o, int n4) {
  int i = blockIdx.x * blockDim.x + threadIdx.x;
  int stride = gridDim.x * blockDim.x;
  for (; i < n4; i += stride) {
    float4 v = w[i];
    ushort4 r;
    r.x = v.x > 0.f ? 0x3F80 : (v.x < 0.f ? 0xBF80 : 0);
    r.y = v.y > 0.f ? 0x3F80 : (v.y < 0.f ? 0xBF80 : 0);
    r.z = v.z > 0.f ? 0x3F80 : (v.z < 0.f ? 0xBF80 : 0);
    r.w = v.w > 0.f ? 0x3F80 : (v.w < 0.f ? 0xBF80 : 0);
    o[i] = r;
  }
}

// ---------------- main GEMM: C[M][N] = A[M][K](bf16) * B[N][K](bf16)^T -------
// m97 structure: 128x128 tile, BK=32, 4 waves 2x2, global_load_lds staging,
// double-buffered LDS, one barrier per K-step.
__global__ __launch_bounds__(256) void bin_gemm(const __bf16* __restrict__ A,
                                                const __bf16* __restrict__ B,
                                                float* __restrict__ C) {
  // LDS layout (elements): A0[0,4096) B0[4096,8192) A1[8192,12288) B1[12288,16384)
  __shared__ __bf16 lds[4 * BM * BK];   // 32 KiB

  const int tid  = threadIdx.x;
  const int w    = tid >> 6;
  const int lane = tid & 63;
  const int lr   = lane & 15;   // fragment row/col within 16
  const int lk   = lane >> 4;   // k-group (0..3)
  const int wr   = w >> 1;      // wave row (0..1)
  const int wc   = w & 1;       // wave col (0..1)

  const int nbn = N_OUT / BN;   // 32
  const int bm  = blockIdx.x / nbn;
  const int bn  = blockIdx.x % nbn;

  const __bf16* Ag = A + (size_t)bm * BM * K_IN;
  const __bf16* Bg = B + (size_t)bn * BN * K_IN;

  f32x4 acc[4][4];
  #pragma unroll
  for (int m = 0; m < 4; ++m)
    #pragma unroll
    for (int n = 0; n < 4; ++n) { f32x4 z = {0.f, 0.f, 0.f, 0.f}; acc[m][n] = z; }

  // per-lane fragment element offsets within a tile [128][32]
  const int a_el = (wr * 64 + lr) * BK + lk * 8;
  const int b_el = (wc * 64 + lr) * BK + lk * 8;

  auto stage = [&](int buf, int t) {
    const int k0 = t * BK;
    #pragma unroll
    for (int j = 0; j < 2; ++j) {
      const int c = w * 128 + j * 64 + lane;       // 16B chunk id, 0..511
      const __bf16* ga = Ag + (size_t)(c >> 2) * K_IN + k0 + (c & 3) * 8;
      const __bf16* gb = Bg + (size_t)(c >> 2) * K_IN + k0 + (c & 3) * 8;
      GLOAD_LDS16(ga, &lds[buf * 8192 + (w * 128 + j * 64) * 8]);
      GLOAD_LDS16(gb, &lds[buf * 8192 + 4096 + (w * 128 + j * 64) * 8]);
    }
  };

  auto compute = [&](int buf) {
    bf16x8 af[4], bfr[4];
    #pragma unroll
    for (int m = 0; m < 4; ++m)
      af[m] = *(const bf16x8*)&lds[buf * 8192 + a_el + m * 16 * BK];
    #pragma unroll
    for (int n = 0; n < 4; ++n)
      bfr[n] = *(const bf16x8*)&lds[buf * 8192 + 4096 + b_el + n * 16 * BK];
    #pragma unroll
    for (int m = 0; m < 4; ++m)
      #pragma unroll
      for (int n = 0; n < 4; ++n)
        acc[m][n] = __builtin_amdgcn_mfma_f32_16x16x32_bf16(af[m], bfr[n], acc[m][n], 0, 0, 0);
  };

  stage(0, 0);
  __syncthreads();                 // compiler drains vmcnt before s_barrier
  int cur = 0;
  for (int t = 0; t < NT - 1; ++t) {
    stage(cur ^ 1, t + 1);         // prefetch next tile (other buffer)
    compute(cur);                  // ds_read + MFMA current buffer
    __syncthreads();               // drain vmcnt+lgkmcnt, flip
    cur ^= 1;
  }
  compute(cur);

  // epilogue: C/D layout col=lane&15, row=(lane>>4)*4+reg  [m89-verified]
  float* Cp = C + (size_t)(bm * BM + wr * 64) * N_OUT + bn * BN + wc * 64;
  #pragma unroll
  for (int m = 0; m < 4; ++m)
    #pragma unroll
    for (int n = 0; n < 4; ++n)
      #pragma unroll
      for (int j = 0; j < 4; ++j)
        Cp[(size_t)(m * 16 + lk * 4 + j) * N_OUT + n * 16 + lr] = acc[m][n][j];
}

// ---------------- fallback (ws too small): fp32 LDS-tiled, correct but slow --
__global__ __launch_bounds__(256) void fb_gemm(const float* __restrict__ x,
                                               const float* __restrict__ W,
                                               float* __restrict__ y) {
  __shared__ float xs[32][33];
  __shared__ float ws[32][33];
  const int bx = blockIdx.x;          // N/32
  const int by = blockIdx.y;          // M/32
  const int tx = threadIdx.x & 31;
  const int ty = threadIdx.x >> 5;    // 0..7
  float acc[4] = {0.f, 0.f, 0.f, 0.f};
  for (int k0 = 0; k0 < K_IN; k0 += 32) {
    #pragma unroll
    for (int i = 0; i < 4; ++i) {
      int r = ty + i * 8;
      xs[r][tx] = x[(size_t)(by * 32 + r) * K_IN + k0 + tx];
      float wv = W[(size_t)(bx * 32 + r) * K_IN + k0 + tx];
      ws[r][tx] = wv > 0.f ? 1.f : (wv < 0.f ? -1.f : 0.f);
    }
    __syncthreads();
    #pragma unroll
    for (int i = 0; i < 4; ++i) {
      int r = ty + i * 8;
      float s = acc[i];
      #pragma unroll
      for (int k = 0; k < 32; ++k) s += xs[r][k] * ws[tx][k];
      acc[i] = s;
    }
    __syncthreads();
  }
  #pragma unroll
  for (int i = 0; i < 4; ++i)
    y[(size_t)(by * 32 + ty + i * 8) * N_OUT + bx * 32 + tx] = acc[i];
}

extern "C" void kernel_launch(void* const* d_in, const int* in_sizes, int n_in,
                              void* d_out, int out_size, void* d_ws, size_t ws_size,
                              hipStream_t stream) {
  const float* x = (const float*)d_in[0];   // [8192, 4096]
  const float* W = (const float*)d_in[1];   // [4096, 4096]
  float* y = (float*)d_out;                 // [8192, 4096]

  const size_t need = ((size_t)M_TOK * K_IN + (size_t)N_OUT * K_IN) * 2;
  if (ws_size >= need) {
    __bf16* xb = (__bf16*)d_ws;
    __bf16* wb = xb + (size_t)M_TOK * K_IN;
    cvt_x_bf16<<<2048, 256, 0, stream>>>((const float4*)x, (ushort4*)xb, M_TOK * K_IN / 4);
    sgn_w_bf16<<<2048, 256, 0, stream>>>((const float4*)W, (ushort4*)wb, N_OUT * K_IN / 4);
    bin_gemm<<<(M_TOK / BM) * (N_OUT / BN), 256, 0, stream>>>(xb, wb, y);
  } else {
    dim3 g(N_OUT / 32, M_TOK / 32);
    fb_gemm<<<g, 256, 0, stream>>>(x, W, y);
  }
}

// Round 2
// 290.051 us; speedup vs baseline: 1.3479x; 1.3479x over previous
//
#include <hip/hip_runtime.h>
#include <hip/hip_bf16.h>
#include <stdint.h>

#define M_TOK 8192
#define N_OUT 4096
#define K_IN  4096

#define BM 256
#define BN 256
#define BK 64
#define NT (K_IN / BK)   // 64 K-tiles

typedef __attribute__((ext_vector_type(8))) __bf16 bf16x8;
typedef __attribute__((ext_vector_type(4))) float  f32x4;

#define AS1 __attribute__((address_space(1)))
#define AS3 __attribute__((address_space(3)))
#define GLOAD_LDS16(g, l) \
  __builtin_amdgcn_global_load_lds((AS1 void*)(g), (AS3 void*)(l), 16, 0, 0)

#define BAR()    __builtin_amdgcn_s_barrier()
#define LGKM0()  do { asm volatile("s_waitcnt lgkmcnt(0)" ::: "memory"); \
                      __builtin_amdgcn_sched_barrier(0); } while (0)
#define VMCNT6() asm volatile("s_waitcnt vmcnt(6)" ::: "memory")
#define VMCNT0() asm volatile("s_waitcnt vmcnt(0)" ::: "memory")
#define PRIO(p)  __builtin_amdgcn_s_setprio(p)

// ---------------- prep: x fp32 -> bf16 (RNE via fptrunc) ----------------
__global__ __launch_bounds__(256) void cvt_x_bf16(const float4* __restrict__ x,
                                                  ushort4* __restrict__ o, int n4) {
  int i = blockIdx.x * blockDim.x + threadIdx.x;
  int stride = gridDim.x * blockDim.x;
  for (; i < n4; i += stride) {
    float4 v = x[i];
    ushort4 r;
    r.x = __builtin_bit_cast(unsigned short, (__bf16)v.x);
    r.y = __builtin_bit_cast(unsigned short, (__bf16)v.y);
    r.z = __builtin_bit_cast(unsigned short, (__bf16)v.z);
    r.w = __builtin_bit_cast(unsigned short, (__bf16)v.w);
    o[i] = r;
  }
}

// ---------------- prep: W fp32 -> sign in bf16 ----------------
__global__ __launch_bounds__(256) void sgn_w_bf16(const float4* __restrict__ w,
                                                  ushort4* __restrict__ o, int n4) {
  int i = blockIdx.x * blockDim.x + threadIdx.x;
  int stride = gridDim.x * blockDim.x;
  for (; i < n4; i += stride) {
    float4 v = w[i];
    ushort4 r;
    r.x = v.x > 0.f ? 0x3F80 : (v.x < 0.f ? 0xBF80 : 0);
    r.y = v.y > 0.f ? 0x3F80 : (v.y < 0.f ? 0xBF80 : 0);
    r.z = v.z > 0.f ? 0x3F80 : (v.z < 0.f ? 0xBF80 : 0);
    r.w = v.w > 0.f ? 0x3F80 : (v.w < 0.f ? 0xBF80 : 0);
    o[i] = r;
  }
}

// ======== 256x256 8-phase GEMM: C[M][N] = A[M][K] * B[N][K]^T (bf16 in, f32 out)
// 8 waves (2Mx4N), BK=64, 128 KiB LDS double-buffer, T2 XOR-swizzle,
// counted vmcnt(6) once per K-tile, setprio around MFMA clusters.
__global__ __launch_bounds__(512, 2) void bin_gemm256(const __bf16* __restrict__ A,
                                                      const __bf16* __restrict__ B,
                                                      float* __restrict__ C) {
  // buffer b at b*65536: A-tile [256 rows][128 B] at +0, B-tile at +32768.
  // Each tile split in 2 halves of 128 rows (16384 B each).
  __shared__ char lds[131072];

  const int tid  = threadIdx.x;
  const int w    = tid >> 6;
  const int lane = tid & 63;
  const int lr   = lane & 15;    // fragment row/col
  const int lk   = lane >> 4;    // k-group 0..3
  const int wr   = w >> 2;       // wave row 0..1  (128 rows each)
  const int wc   = w & 3;        // wave col 0..3  (64 cols each)

  const int bm = blockIdx.x >> 4;     // M/256 = 32
  const int bn = blockIdx.x & 15;     // N/256 = 16

  const char* Ag = (const char*)(A + (size_t)bm * BM * K_IN);
  const char* Bg = (const char*)(B + (size_t)bn * BN * K_IN);

  // ---- staging: per-lane pre-swizzled global offsets (rule #21: linear LDS
  // dest, inverse-swizzled source). Chunk c (16B units) of a 128-row half:
  // row r = c>>3, source slot = (c ^ r) & 7.
  const int c0 = w * 128 + lane;            // load j=0
  const int c1 = c0 + 64;                   // load j=1
  const int r0 = c0 >> 3, r1 = c1 >> 3;
  const size_t g0 = (size_t)r0 * (K_IN * 2) + (size_t)(((c0 ^ r0) & 7) << 4);
  const size_t g1 = (size_t)r1 * (K_IN * 2) + (size_t)(((c1 ^ r1) & 7) << 4);
  const int ldsw = w * 128 * 16;            // wave-uniform chunk base (bytes)

  auto stage = [&](int mat, int half, int tt) {
    const char* g = (mat ? Bg : Ag) + (size_t)half * (128 * K_IN * 2)
                                    + (size_t)tt * (BK * 2);
    char* l = &lds[((tt & 1) << 16) + (mat << 15) + (half << 14) + ldsw];
    GLOAD_LDS16(g + g0, l);
    GLOAD_LDS16(g + g1, l + 1024);
  };

  // ---- fragment-read addressing (swizzled): byte off within a tile region:
  // (row)*128 + ((s*64 + lk*16) ^ ((row&7)<<4)); row&7 == lr&7 for all frags.
  const int swz  = (lr & 7) << 4;
  const int a_row = (wr * 128 + lr) * 128;            // A region base row
  const int b_row = 32768 + (wc * 64 + lr) * 128;     // B region
  const int k0 = (lk * 16) ^ swz;                     // k-slice 0
  const int k1 = (64 + lk * 16) ^ swz;                // k-slice 1

  f32x4 acc[8][4];
  #pragma unroll
  for (int m = 0; m < 8; ++m)
    #pragma unroll
    for (int n = 0; n < 4; ++n) { f32x4 z = {0.f,0.f,0.f,0.f}; acc[m][n] = z; }

  // ---- prologue: tile 0 complete + {B0,B1,A0}(1) in flight (6 loads)
  stage(0, 0, 0); stage(0, 1, 0); stage(1, 0, 0); stage(1, 1, 0);
  stage(1, 0, 1); stage(1, 1, 1); stage(0, 0, 1);
  VMCNT6();
  BAR();

  for (int t = 0; t < NT; ++t) {
    const char* L = &lds[(size_t)(t & 1) << 16];
    bf16x8 aF[4][2], aS[4][2], bF[4][2];

    // ---------- phase 0: read a[0..3], b[0..1]; stage A1(t+1); MFMA m0-3 x n0-1
    #pragma unroll
    for (int m = 0; m < 4; ++m) {
      aF[m][0] = *(const bf16x8*)(L + a_row + m * 2048 + k0);
      aF[m][1] = *(const bf16x8*)(L + a_row + m * 2048 + k1);
    }
    #pragma unroll
    for (int n = 0; n < 2; ++n) {
      bF[n][0] = *(const bf16x8*)(L + b_row + n * 2048 + k0);
      bF[n][1] = *(const bf16x8*)(L + b_row + n * 2048 + k1);
    }
    if (t + 1 < NT) stage(0, 1, t + 1);
    BAR(); LGKM0(); PRIO(1);
    #pragma unroll
    for (int m = 0; m < 4; ++m)
      #pragma unroll
      for (int n = 0; n < 2; ++n) {
        acc[m][n] = __builtin_amdgcn_mfma_f32_16x16x32_bf16(aF[m][0], bF[n][0], acc[m][n], 0, 0, 0);
        acc[m][n] = __builtin_amdgcn_mfma_f32_16x16x32_bf16(aF[m][1], bF[n][1], acc[m][n], 0, 0, 0);
      }
    PRIO(0); BAR();

    // ---------- phase 1: read b[2..3]; MFMA m0-3 x n2-3
    #pragma unroll
    for (int n = 2; n < 4; ++n) {
      bF[n][0] = *(const bf16x8*)(L + b_row + n * 2048 + k0);
      bF[n][1] = *(const bf16x8*)(L + b_row + n * 2048 + k1);
    }
    BAR(); LGKM0(); PRIO(1);
    #pragma unroll
    for (int m = 0; m < 4; ++m)
      #pragma unroll
      for (int n = 2; n < 4; ++n) {
        acc[m][n] = __builtin_amdgcn_mfma_f32_16x16x32_bf16(aF[m][0], bF[n][0], acc[m][n], 0, 0, 0);
        acc[m][n] = __builtin_amdgcn_mfma_f32_16x16x32_bf16(aF[m][1], bF[n][1], acc[m][n], 0, 0, 0);
      }
    PRIO(0); BAR();

    // ---------- phase 2: read a[4..7]; stage B0(t+2); MFMA m4-7 x n0-1
    #pragma unroll
    for (int m = 0; m < 4; ++m) {
      aS[m][0] = *(const bf16x8*)(L + a_row + 8192 + m * 2048 + k0);
      aS[m][1] = *(const bf16x8*)(L + a_row + 8192 + m * 2048 + k1);
    }
    if (t + 2 < NT) stage(1, 0, t + 2);
    BAR(); LGKM0(); PRIO(1);
    #pragma unroll
    for (int m = 0; m < 4; ++m)
      #pragma unroll
      for (int n = 0; n < 2; ++n) {
        acc[4 + m][n] = __builtin_amdgcn_mfma_f32_16x16x32_bf16(aS[m][0], bF[n][0], acc[4 + m][n], 0, 0, 0);
        acc[4 + m][n] = __builtin_amdgcn_mfma_f32_16x16x32_bf16(aS[m][1], bF[n][1], acc[4 + m][n], 0, 0, 0);
      }
    PRIO(0); BAR();

    // ---------- phase 3: stage B1(t+2), A0(t+2); MFMA m4-7 x n2-3; boundary vmcnt
    if (t + 2 < NT) { stage(1, 1, t + 2); stage(0, 0, t + 2); }
    BAR(); PRIO(1);
    #pragma unroll
    for (int m = 0; m < 4; ++m)
      #pragma unroll
      for (int n = 2; n < 4; ++n) {
        acc[4 + m][n] = __builtin_amdgcn_mfma_f32_16x16x32_bf16(aS[m][0], bF[n][0], acc[4 + m][n], 0, 0, 0);
        acc[4 + m][n] = __builtin_amdgcn_mfma_f32_16x16x32_bf16(aS[m][1], bF[n][1], acc[4 + m][n], 0, 0, 0);
      }
    PRIO(0);
    if (t < NT - 2) { VMCNT6(); } else { VMCNT0(); }
    BAR();
  }

  // ---------- epilogue: C/D layout col=lane&15, row=(lane>>4)*4+reg
  float* Cp = C + (size_t)(bm * BM + wr * 128) * N_OUT + bn * BN + wc * 64;
  #pragma unroll
  for (int m = 0; m < 8; ++m)
    #pragma unroll
    for (int n = 0; n < 4; ++n)
      #pragma unroll
      for (int j = 0; j < 4; ++j)
        Cp[(size_t)(m * 16 + lk * 4 + j) * N_OUT + n * 16 + lr] = acc[m][n][j];
}

// ---------------- fallback (ws too small): fp32 LDS-tiled, correct but slow --
__global__ __launch_bounds__(256) void fb_gemm(const float* __restrict__ x,
                                               const float* __restrict__ W,
                                               float* __restrict__ y) {
  __shared__ float xs[32][33];
  __shared__ float ws[32][33];
  const int bx = blockIdx.x;
  const int by = blockIdx.y;
  const int tx = threadIdx.x & 31;
  const int ty = threadIdx.x >> 5;
  float acc[4] = {0.f, 0.f, 0.f, 0.f};
  for (int k0 = 0; k0 < K_IN; k0 += 32) {
    #pragma unroll
    for (int i = 0; i < 4; ++i) {
      int r = ty + i * 8;
      xs[r][tx] = x[(size_t)(by * 32 + r) * K_IN + k0 + tx];
      float wv = W[(size_t)(bx * 32 + r) * K_IN + k0 + tx];
      ws[r][tx] = wv > 0.f ? 1.f : (wv < 0.f ? -1.f : 0.f);
    }
    __syncthreads();
    #pragma unroll
    for (int i = 0; i < 4; ++i) {
      int r = ty + i * 8;
      float s = acc[i];
      #pragma unroll
      for (int k = 0; k < 32; ++k) s += xs[r][k] * ws[tx][k];
      acc[i] = s;
    }
    __syncthreads();
  }
  #pragma unroll
  for (int i = 0; i < 4; ++i)
    y[(size_t)(by * 32 + ty + i * 8) * K_IN + bx * 32 + tx] = acc[i];
}

extern "C" void kernel_launch(void* const* d_in, const int* in_sizes, int n_in,
                              void* d_out, int out_size, void* d_ws, size_t ws_size,
                              hipStream_t stream) {
  const float* x = (const float*)d_in[0];   // [8192, 4096]
  const float* W = (const float*)d_in[1];   // [4096, 4096]
  float* y = (float*)d_out;                 // [8192, 4096]

  const size_t need = ((size_t)M_TOK * K_IN + (size_t)N_OUT * K_IN) * 2;
  if (ws_size >= need) {
    __bf16* xb = (__bf16*)d_ws;
    __bf16* wb = xb + (size_t)M_TOK * K_IN;
    cvt_x_bf16<<<2048, 256, 0, stream>>>((const float4*)x, (ushort4*)xb, M_TOK * K_IN / 4);
    sgn_w_bf16<<<2048, 256, 0, stream>>>((const float4*)W, (ushort4*)wb, N_OUT * K_IN / 4);
    bin_gemm256<<<(M_TOK / BM) * (N_OUT / BN), 512, 0, stream>>>(xb, wb, y);
  } else {
    dim3 g(N_OUT / 32, M_TOK / 32);
    fb_gemm<<<g, 256, 0, stream>>>(x, W, y);
  }
}